// Round 14
// baseline (88.006 us; speedup 1.0000x reference)
//
#include <hip/hip_runtime.h>

// Problem constants (match reference)
#define NB 32
#define CH 3
#define HH 768
#define WW 768

// Tiling
#define TW 64                   // tile width
#define TH 16                   // tile height
#define SW 72                   // staged (used) width: [tw0-4, tw0+68)
#define SWP 76                  // LDS row stride
#define SH (TH + 4)             // 20 staged rows
#define CSTRIDE (SH * SWP)      // floats per channel plane
#define TPB 8                   // tiles per block (vertical chain, 128 rows)
#define NTC (WW / TW)           // 12
#define NTG (HH / (TH * TPB))   // 6
#define NWG (NB * NTC * NTG)    // 2304, %8==0
#define UNITS (SH * (SW / 4))   // 360 float4-units per tile
#define NT 128                  // threads per block: 16 tx x 8 ty
#define RY 2

typedef float v4f __attribute__((ext_vector_type(4)));  // for NT stores

// Pair-swap swizzle: logical within-row float f lives at physical
// f ^ (((f>>5)&1)<<1). Conv reads at s in {4tx+2,4tx+4,4tx+6,4tx+8} then
// cover all 32 banks exactly once across the 16 tx lanes -> conflict-free.
__device__ inline int pswz(int s) { return s ^ (((s >> 5) & 1) << 1); }

__global__ __launch_bounds__(NT) void colwarp_conv_kernel(
    const float* __restrict__ im,
    const float* __restrict__ flat,
    float* __restrict__ out)
{
    // XCD-contiguous mapping; one XCD owns whole images (4 each).
    const int d   = blockIdx.x;
    const int wid = (d & 7) * (NWG / 8) + (d >> 3);
    const int tc  = wid % NTC;
    const int t2  = wid / NTC;
    const int tg  = t2 % NTG;
    const int b   = t2 / NTG;
    const int tw0 = tc * TW;
    const int thbase = tg * (TPB * TH);

    // SINGLE buffer: 3*20*76*4 = 18240 B -> LDS allows 8 blocks/CU
    __shared__ float xs[CH][SH][SWP];

    const int tid = threadIdx.x;

    // ---- per-sample params (b block-uniform -> scalar) ----
    const float* f = flat + b * 37;
    float Wm[3][3];
#pragma unroll
    for (int i = 0; i < 3; ++i)
#pragma unroll
        for (int j = 0; j < 3; ++j) Wm[i][j] = f[i * 3 + j];
    float sh3[3];
#pragma unroll
    for (int i = 0; i < 3; ++i) sh3[i] = f[9 + i];
    float K[5][5];
#pragma unroll
    for (int i = 0; i < 5; ++i)
#pragma unroll
        for (int j = 0; j < 5; ++j) K[i][j] = f[12 + i * 5 + j];
    float bias[3];
#pragma unroll
    for (int c = 0; c < 3; ++c)
        bias[c] = sh3[0]*Wm[0][c] + sh3[1]*Wm[1][c] + sh3[2]*Wm[2][c];

    const size_t plane = (size_t)HH * WW;
    const float* im0 = im + (size_t)b * CH * plane;

    // ---- this thread's staging units: u, u+128, u+256 (360 total) ----
    int ur[3], uldso[3], ugw[3];
    bool uon[3], uswap[3];
#pragma unroll
    for (int ui = 0; ui < 3; ++ui) {
        const int u  = tid + NT * ui;
        const int rr = u / (SW / 4);
        const int c4 = u - rr * (SW / 4);     // granule 0..17
        ur[ui]    = rr;
        uldso[ui] = rr * SWP + c4 * 4;        // linear granule address
        ugw[ui]   = tw0 - 4 + c4 * 4;
        uon[ui]   = (u < UNITS);
        uswap[ui] = ((c4 >> 3) & 1) != 0;     // granules 8..15: swap halves
    }

    float4 vld[3][CH];   // in-flight raw loads (36 floats)
    bool vok[3];

#define STAGE_LOAD(TH0)                                                        \
    _Pragma("unroll")                                                          \
    for (int ui = 0; ui < 3; ++ui) {                                           \
        const int gh = (TH0) + ur[ui] - 2;                                     \
        const bool ok = uon[ui] && ((unsigned)gh < (unsigned)HH)               \
                                && ((unsigned)ugw[ui] < (unsigned)WW);         \
        vok[ui] = ok;                                                          \
        if (ok) {                                                              \
            const size_t off = (size_t)gh * WW + ugw[ui];                      \
            vld[ui][0] = *(const float4*)(im0 + off);                          \
            vld[ui][1] = *(const float4*)(im0 + plane + off);                  \
            vld[ui][2] = *(const float4*)(im0 + 2 * plane + off);              \
        }                                                                      \
    }

#define STAGE_WRITE(BUFP)                                                      \
    _Pragma("unroll")                                                          \
    for (int ui = 0; ui < 3; ++ui) {                                           \
        if (uon[ui]) {                                                         \
            float4 m0 = make_float4(0.f, 0.f, 0.f, 0.f), m1 = m0, m2 = m0;     \
            if (vok[ui]) {                                                     \
                const float4 a0 = vld[ui][0], a1 = vld[ui][1], a2 = vld[ui][2];\
                m0.x = a0.x*Wm[0][0] + a1.x*Wm[1][0] + a2.x*Wm[2][0] + bias[0];\
                m0.y = a0.y*Wm[0][0] + a1.y*Wm[1][0] + a2.y*Wm[2][0] + bias[0];\
                m0.z = a0.z*Wm[0][0] + a1.z*Wm[1][0] + a2.z*Wm[2][0] + bias[0];\
                m0.w = a0.w*Wm[0][0] + a1.w*Wm[1][0] + a2.w*Wm[2][0] + bias[0];\
                m1.x = a0.x*Wm[0][1] + a1.x*Wm[1][1] + a2.x*Wm[2][1] + bias[1];\
                m1.y = a0.y*Wm[0][1] + a1.y*Wm[1][1] + a2.y*Wm[2][1] + bias[1];\
                m1.z = a0.z*Wm[0][1] + a1.z*Wm[1][1] + a2.z*Wm[2][1] + bias[1];\
                m1.w = a0.w*Wm[0][1] + a1.w*Wm[1][1] + a2.w*Wm[2][1] + bias[1];\
                m2.x = a0.x*Wm[0][2] + a1.x*Wm[1][2] + a2.x*Wm[2][2] + bias[2];\
                m2.y = a0.y*Wm[0][2] + a1.y*Wm[1][2] + a2.y*Wm[2][2] + bias[2];\
                m2.z = a0.z*Wm[0][2] + a1.z*Wm[1][2] + a2.z*Wm[2][2] + bias[2];\
                m2.w = a0.w*Wm[0][2] + a1.w*Wm[1][2] + a2.w*Wm[2][2] + bias[2];\
            }                                                                  \
            const bool sw = uswap[ui];                                         \
            const float4 w0 = sw ? make_float4(m0.z,m0.w,m0.x,m0.y) : m0;      \
            const float4 w1 = sw ? make_float4(m1.z,m1.w,m1.x,m1.y) : m1;      \
            const float4 w2 = sw ? make_float4(m2.z,m2.w,m2.x,m2.y) : m2;      \
            *(float4*)((BUFP) + 0 * CSTRIDE + uldso[ui]) = w0;                 \
            *(float4*)((BUFP) + 1 * CSTRIDE + uldso[ui]) = w1;                 \
            *(float4*)((BUFP) + 2 * CSTRIDE + uldso[ui]) = w2;                 \
        }                                                                      \
    }

    const int tx = tid & 15;      // 4 output cols
    const int ty = tid >> 4;      // 0..7, 2 output rows each
    const int r0 = ty * RY;

    // Conv window logical floats 4tx+2..4tx+9 as 4 float2 pairs (pair-swizzled):
    const int offA = pswz(4 * tx + 2);
    const int offB = pswz(4 * tx + 4);
    const int offC = pswz(4 * tx + 6);
    const int offD = pswz(4 * tx + 8);

#define CONV_STORE(BUFP, TH0)                                                  \
    {                                                                          \
        float acc[CH][RY][4];                                                  \
        _Pragma("unroll")                                                      \
        for (int c = 0; c < CH; ++c)                                           \
            _Pragma("unroll")                                                  \
            for (int r = 0; r < RY; ++r)                                       \
                _Pragma("unroll")                                              \
                for (int o = 0; o < 4; ++o) acc[c][r][o] = 0.f;                \
        _Pragma("unroll")                                                      \
        for (int rr = 0; rr < RY + 4; ++rr) {                                  \
            _Pragma("unroll")                                                  \
            for (int c = 0; c < CH; ++c) {                                     \
                const float* rowb = (BUFP) + c * CSTRIDE + (r0 + rr) * SWP;    \
                const float2 p0 = *(const float2*)(rowb + offA);               \
                const float2 p1 = *(const float2*)(rowb + offB);               \
                const float2 p2 = *(const float2*)(rowb + offC);               \
                const float2 p3 = *(const float2*)(rowb + offD);               \
                const float w8[8] = {p0.x, p0.y, p1.x, p1.y,                   \
                                     p2.x, p2.y, p3.x, p3.y};                  \
                _Pragma("unroll")                                              \
                for (int i = 0; i < 5; ++i) {                                  \
                    const int r = rr - i;                                      \
                    if (r >= 0 && r < RY) {                                    \
                        _Pragma("unroll")                                      \
                        for (int j = 0; j < 5; ++j) {                          \
                            _Pragma("unroll")                                  \
                            for (int o = 0; o < 4; ++o)                        \
                                acc[c][r][o] += w8[o + j] * K[i][j];           \
                        }                                                      \
                    }                                                          \
                }                                                              \
            }                                                                  \
        }                                                                      \
        _Pragma("unroll")                                                      \
        for (int c = 0; c < CH; ++c) {                                         \
            float* ob = out + ((size_t)b * CH + c) * plane;                    \
            _Pragma("unroll")                                                  \
            for (int r = 0; r < RY; ++r) {                                     \
                v4f vv = {acc[c][r][0], acc[c][r][1],                          \
                          acc[c][r][2], acc[c][r][3]};                         \
                __builtin_nontemporal_store(vv,                                \
                    (v4f*)&ob[(size_t)((TH0) + r0 + r) * WW + tw0 + tx * 4]);  \
            }                                                                  \
        }                                                                      \
    }

    // ---- prologue: stage tile 0 ----
    STAGE_LOAD(thbase);
    STAGE_WRITE(&xs[0][0][0]);
    __syncthreads();

    // ---- chained single-buffer pipeline: load-early, write-late ----
#pragma unroll 1
    for (int t = 0; t < TPB; ++t) {
        const int th0 = thbase + t * TH;
        if (t + 1 < TPB) { STAGE_LOAD(th0 + TH); }   // HBM issue hides under conv
        CONV_STORE(&xs[0][0][0], th0);
        __syncthreads();                              // all reads of buffer done
        if (t + 1 < TPB) {
            STAGE_WRITE(&xs[0][0][0]);                // mix + write next tile
            __syncthreads();                          // buffer ready
        }
    }
}

extern "C" void kernel_launch(void* const* d_in, const int* in_sizes, int n_in,
                              void* d_out, int out_size, void* d_ws, size_t ws_size,
                              hipStream_t stream) {
    const float* im   = (const float*)d_in[0];
    const float* flat = (const float*)d_in[1];
    float* out        = (float*)d_out;

    colwarp_conv_kernel<<<dim3(NWG), dim3(NT), 0, stream>>>(im, flat, out);
}

// Round 15
// 83.026 us; speedup vs baseline: 1.0600x; 1.0600x over previous
//
#include <hip/hip_runtime.h>

// Problem constants (match reference)
#define NB 32
#define CH 3
#define HH 768
#define WW 768

// Wave-autonomous streaming: each 64-lane wave owns a 64-wide x 96-row band,
// streams down with a private 12-row LDS ring. NO __syncthreads anywhere —
// within-wave ordering via compiler-inserted lgkmcnt/vmcnt only.
#define TW 64
#define SW 72                   // staged width: [tw0-4, tw0+68)
#define SWP 76                  // LDS row stride (floats)
#define RING 12                 // ring rows (alive set per step)
#define CROWS 96                // output rows per wave
#define NSTEP (CROWS / 8)       // 12 steps x 8 output rows
#define GRAN (SW / 4)           // 18 float4 granules per row
#define NTC (WW / TW)           // 12
#define NVC (HH / CROWS)        // 8
#define NWG (NB * NTC * NVC)    // 3072, %8==0
#define RY 2

typedef float v4f __attribute__((ext_vector_type(4)));  // NT stores

// Pair-swap swizzle (R11, proven -91% conflicts): logical in-row float f at
// physical f ^ (((f>>5)&1)<<1); granules 8..15 store halves swapped.
__device__ inline int pswz(int s) { return s ^ (((s >> 5) & 1) << 1); }

__global__ __launch_bounds__(64) void colwarp_conv_kernel(
    const float* __restrict__ im,
    const float* __restrict__ flat,
    float* __restrict__ out)
{
    // XCD-contiguous mapping: each XCD owns a contiguous 1/8 of all bands.
    const int d   = blockIdx.x;
    const int wid = (d & 7) * (NWG / 8) + (d >> 3);
    const int tc  = wid % NTC;
    const int t2  = wid / NTC;
    const int vc  = t2 % NVC;
    const int b   = t2 / NVC;
    const int tw0   = tc * TW;
    const int rbase = vc * CROWS;      // first output row of this band

    __shared__ float xs[RING][CH][SWP];   // 10944 B -> 12+ blocks/CU

    const int lane = threadIdx.x;         // one wave per block

    // ---- per-sample params (b block-uniform -> scalar) ----
    const float* f = flat + b * 37;
    float Wm[3][3];
#pragma unroll
    for (int i = 0; i < 3; ++i)
#pragma unroll
        for (int j = 0; j < 3; ++j) Wm[i][j] = f[i * 3 + j];
    float sh3[3];
#pragma unroll
    for (int i = 0; i < 3; ++i) sh3[i] = f[9 + i];
    float K[5][5];
#pragma unroll
    for (int i = 0; i < 5; ++i)
#pragma unroll
        for (int j = 0; j < 5; ++j) K[i][j] = f[12 + i * 5 + j];
    float bias[3];
#pragma unroll
    for (int c = 0; c < 3; ++c)
        bias[c] = sh3[0]*Wm[0][c] + sh3[1]*Wm[1][c] + sh3[2]*Wm[2][c];

    const size_t plane = (size_t)HH * WW;
    const float* im0 = im + (size_t)b * CH * plane;

    // ---- staging unit descriptors (step-invariant): unit u = lane + 64*ui
    //      covers group-row urow = u/18, granule g = u%18. ----
    int urow[4], ugw[4], uldc[4];
    bool uswap[4];
#pragma unroll
    for (int ui = 0; ui < 4; ++ui) {
        const int u = lane + 64 * ui;
        const int r = u / GRAN;
        const int g = u - r * GRAN;
        urow[ui] = r;
        ugw[ui]  = tw0 - 4 + g * 4;
        uldc[ui] = g * 4;
        uswap[ui] = ((g >> 3) & 1) != 0;
    }

    float4 vla[4][CH];
    bool vok[4];

    // Issue global loads for a group of R rows at band-local row LR0.
#define STAGE_LOAD(LR0, R, NUI)                                                \
    _Pragma("unroll")                                                          \
    for (int ui = 0; ui < (NUI); ++ui) {                                       \
        const bool act = (lane + 64 * ui) < (R) * GRAN;                        \
        const int gh = rbase + (LR0) + urow[ui];                               \
        const bool ok = act && ((unsigned)gh < (unsigned)HH)                   \
                            && ((unsigned)ugw[ui] < (unsigned)WW);             \
        vok[ui] = ok;                                                          \
        if (ok) {                                                              \
            const size_t off = (size_t)gh * WW + ugw[ui];                      \
            vla[ui][0] = *(const float4*)(im0 + off);                          \
            vla[ui][1] = *(const float4*)(im0 + plane + off);                  \
            vla[ui][2] = *(const float4*)(im0 + 2 * plane + off);              \
        }                                                                      \
    }

    // Mix + write the held group into ring slots SLOT0+urow (wrap).
#define STAGE_WRITE(SLOT0, R, NUI)                                             \
    _Pragma("unroll")                                                          \
    for (int ui = 0; ui < (NUI); ++ui) {                                       \
        const bool act = (lane + 64 * ui) < (R) * GRAN;                        \
        if (act) {                                                             \
            float4 m0 = make_float4(0.f, 0.f, 0.f, 0.f), m1 = m0, m2 = m0;     \
            if (vok[ui]) {                                                     \
                const float4 a0 = vla[ui][0], a1 = vla[ui][1], a2 = vla[ui][2];\
                m0.x = a0.x*Wm[0][0] + a1.x*Wm[1][0] + a2.x*Wm[2][0] + bias[0];\
                m0.y = a0.y*Wm[0][0] + a1.y*Wm[1][0] + a2.y*Wm[2][0] + bias[0];\
                m0.z = a0.z*Wm[0][0] + a1.z*Wm[1][0] + a2.z*Wm[2][0] + bias[0];\
                m0.w = a0.w*Wm[0][0] + a1.w*Wm[1][0] + a2.w*Wm[2][0] + bias[0];\
                m1.x = a0.x*Wm[0][1] + a1.x*Wm[1][1] + a2.x*Wm[2][1] + bias[1];\
                m1.y = a0.y*Wm[0][1] + a1.y*Wm[1][1] + a2.y*Wm[2][1] + bias[1];\
                m1.z = a0.z*Wm[0][1] + a1.z*Wm[1][1] + a2.z*Wm[2][1] + bias[1];\
                m1.w = a0.w*Wm[0][1] + a1.w*Wm[1][1] + a2.w*Wm[2][1] + bias[1];\
                m2.x = a0.x*Wm[0][2] + a1.x*Wm[1][2] + a2.x*Wm[2][2] + bias[2];\
                m2.y = a0.y*Wm[0][2] + a1.y*Wm[1][2] + a2.y*Wm[2][2] + bias[2];\
                m2.z = a0.z*Wm[0][2] + a1.z*Wm[1][2] + a2.z*Wm[2][2] + bias[2];\
                m2.w = a0.w*Wm[0][2] + a1.w*Wm[1][2] + a2.w*Wm[2][2] + bias[2];\
            }                                                                  \
            const bool sw = uswap[ui];                                         \
            const float4 w0 = sw ? make_float4(m0.z,m0.w,m0.x,m0.y) : m0;      \
            const float4 w1 = sw ? make_float4(m1.z,m1.w,m1.x,m1.y) : m1;      \
            const float4 w2 = sw ? make_float4(m2.z,m2.w,m2.x,m2.y) : m2;      \
            int slot = (SLOT0) + urow[ui];                                     \
            if (slot >= RING) slot -= RING;                                    \
            float* bp = &xs[slot][0][0] + uldc[ui];                            \
            *(float4*)(bp)           = w0;                                     \
            *(float4*)(bp + SWP)     = w1;                                     \
            *(float4*)(bp + 2 * SWP) = w2;                                     \
        }                                                                      \
    }

    const int tx = lane & 15;     // 4 output cols
    const int ty = lane >> 4;     // 0..3, 2 output rows each

    // Conv window logical floats 4tx+2..4tx+9 as 4 float2 pairs (pair-swizzled):
    const int offA = pswz(4 * tx + 2);
    const int offB = pswz(4 * tx + 4);
    const int offC = pswz(4 * tx + 6);
    const int offD = pswz(4 * tx + 8);

    // Conv 8 output rows (band-local S8..S8+7); ring slotbase SB for row S8-2.
#define CONV_STORE(S8, SB)                                                     \
    {                                                                          \
        float acc[CH][RY][4];                                                  \
        _Pragma("unroll")                                                      \
        for (int c = 0; c < CH; ++c)                                           \
            _Pragma("unroll")                                                  \
            for (int r = 0; r < RY; ++r)                                       \
                _Pragma("unroll")                                              \
                for (int o = 0; o < 4; ++o) acc[c][r][o] = 0.f;                \
        _Pragma("unroll")                                                      \
        for (int rr = 0; rr < RY + 4; ++rr) {                                  \
            int slot = (SB) + 2 * ty + rr;                                     \
            if (slot >= RING) slot -= RING;                                    \
            const float* sl = &xs[slot][0][0];                                 \
            _Pragma("unroll")                                                  \
            for (int c = 0; c < CH; ++c) {                                     \
                const float* rowb = sl + c * SWP;                              \
                const float2 p0 = *(const float2*)(rowb + offA);               \
                const float2 p1 = *(const float2*)(rowb + offB);               \
                const float2 p2 = *(const float2*)(rowb + offC);               \
                const float2 p3 = *(const float2*)(rowb + offD);               \
                const float w8[8] = {p0.x, p0.y, p1.x, p1.y,                   \
                                     p2.x, p2.y, p3.x, p3.y};                  \
                _Pragma("unroll")                                              \
                for (int i = 0; i < 5; ++i) {                                  \
                    const int r = rr - i;                                      \
                    if (r >= 0 && r < RY) {                                    \
                        _Pragma("unroll")                                      \
                        for (int j = 0; j < 5; ++j) {                          \
                            _Pragma("unroll")                                  \
                            for (int o = 0; o < 4; ++o)                        \
                                acc[c][r][o] += w8[o + j] * K[i][j];           \
                        }                                                      \
                    }                                                          \
                }                                                              \
            }                                                                  \
        }                                                                      \
        _Pragma("unroll")                                                      \
        for (int c = 0; c < CH; ++c) {                                         \
            float* ob = out + ((size_t)b * CH + c) * plane;                    \
            _Pragma("unroll")                                                  \
            for (int r = 0; r < RY; ++r) {                                     \
                const int orow = rbase + (S8) + 2 * ty + r;                    \
                v4f vv = {acc[c][r][0], acc[c][r][1],                          \
                          acc[c][r][2], acc[c][r][3]};                         \
                __builtin_nontemporal_store(vv,                                \
                    (v4f*)&ob[(size_t)orow * WW + tw0 + tx * 4]);              \
            }                                                                  \
        }                                                                      \
    }

    // ---- prologue: stage band-local rows -2..9 into slots 0..11 ----
    STAGE_LOAD(-2, 12, 4);
    STAGE_WRITE(0, 12, 4);

    // ---- barrier-free steady state ----
    int sb = 0;   // ring slot of band-local row 8s-2 (cycles 0,8,4)
#pragma unroll 1
    for (int s = 0; s < NSTEP; ++s) {
        if (s + 1 < NSTEP) { STAGE_LOAD(8 * s + 10, 8, 3); }  // issue early
        CONV_STORE(8 * s, sb);                                 // hides HBM latency
        if (s + 1 < NSTEP) { STAGE_WRITE(sb, 8, 3); }          // refill dead slots
        sb += 8; if (sb >= RING) sb -= RING;
    }
}

extern "C" void kernel_launch(void* const* d_in, const int* in_sizes, int n_in,
                              void* d_out, int out_size, void* d_ws, size_t ws_size,
                              hipStream_t stream) {
    const float* im   = (const float*)d_in[0];
    const float* flat = (const float*)d_in[1];
    float* out        = (float*)d_out;

    colwarp_conv_kernel<<<dim3(NWG), dim3(64), 0, stream>>>(im, flat, out);
}